// Round 2
// baseline (8600.204 us; speedup 1.0000x reference)
//
#include <hip/hip_runtime.h>
#include <hip/hip_bf16.h>
#include <stdint.h>

#define BB  256
#define TT  512
#define FF  8
#define HH  256
#define H4  1024
#define DEC 35

// ---------------- prep: fp32 -> bf16 weights (+ W_sum = W_x + W_h) ----------------
__global__ void prep_weights(const float* __restrict__ Wx, const float* __restrict__ Wh,
                             __hip_bfloat16* __restrict__ wxb,
                             __hip_bfloat16* __restrict__ whb,
                             __hip_bfloat16* __restrict__ wsb) {
    int i = blockIdx.x * 256 + threadIdx.x;
    if (i < HH * H4) {
        float x = Wx[i], h = Wh[i];
        wxb[i] = __float2bfloat16(x);
        whb[i] = __float2bfloat16(h);
        wsb[i] = __float2bfloat16(x + h);
    }
}

// z-contribution for this thread's two columns (2*tid, 2*tid+1)
template<bool BF16W>
__device__ __forceinline__ void matvec2(const void* __restrict__ W,
                                        const float* __restrict__ vec,
                                        int tid, float& z0, float& z1) {
    if constexpr (BF16W) {
        const uint32_t* Wp = (const uint32_t*)W;   // one dword = bf16 cols (2tid, 2tid+1)
        #pragma unroll 8
        for (int k = 0; k < HH; ++k) {
            uint32_t w = Wp[(size_t)k * (H4 / 2) + tid];
            float s = vec[k];
            union { uint32_t u; float f; } lo, hi;
            lo.u = w << 16;            // low ushort  -> col 2tid
            hi.u = w & 0xffff0000u;    // high ushort -> col 2tid+1
            z0 = fmaf(s, lo.f, z0);
            z1 = fmaf(s, hi.f, z1);
        }
    } else {
        const float2* Wp = (const float2*)W;
        #pragma unroll 8
        for (int k = 0; k < HH; ++k) {
            float2 w = Wp[(size_t)k * (H4 / 2) + tid];
            float s = vec[k];
            z0 = fmaf(s, w.x, z0);
            z1 = fmaf(s, w.y, z1);
        }
    }
}

__device__ __forceinline__ float sigmoidf_(float x) { return 1.0f / (1.0f + expf(-x)); }

// ---------------- main: one workgroup per batch element ----------------
template<bool BF16W>
__global__ __launch_bounds__(512)
void lstm_persist(const float* __restrict__ pulse,
                  const float* __restrict__ bn_gamma, const float* __restrict__ bn_beta,
                  const float* __restrict__ bn_mean, const float* __restrict__ bn_var,
                  const float* __restrict__ W_pe, const float* __restrict__ b_pe,
                  const float* __restrict__ embed,
                  const float* __restrict__ W_x, const float* __restrict__ W_h,
                  const float* __restrict__ b_lstm,
                  const float* __restrict__ W_mlp, const float* __restrict__ b_mlp,
                  const float* __restrict__ scale_w, const float* __restrict__ scale_b,
                  const void* __restrict__ WxQ, const void* __restrict__ WhQ,
                  const void* __restrict__ WsQ,
                  float* __restrict__ out) {
    __shared__ float sWpe2[FF * HH];   // bn-scale folded W_pe
    __shared__ float sbpe2[HH];        // bn-shift folded bias
    __shared__ float sbl[H4];          // b_lstm
    __shared__ float sWmlp[HH * 2];
    __shared__ float sbuf[HH];         // LSTM input vector (pe_t / embed)
    __shared__ float hbuf[HH];
    __shared__ float cbuf[HH];
    __shared__ float zbuf[H4];
    __shared__ float bnsc[FF], bnsh[FF];
    __shared__ float smisc[6];         // b_mlp[2], scale_w[2], scale_b[2]

    const int tid = threadIdx.x;
    const int bb  = blockIdx.x;

    // ---- stage constants ----
    if (tid < FF) {
        float s = bn_gamma[tid] * rsqrtf(bn_var[tid] + 1e-3f);
        bnsc[tid] = s;
        bnsh[tid] = bn_beta[tid] - bn_mean[tid] * s;
    }
    if (tid < 2) {
        smisc[tid]     = b_mlp[tid];
        smisc[2 + tid] = scale_w[tid];
        smisc[4 + tid] = scale_b[tid];
    }
    for (int i = tid; i < H4; i += 512) sbl[i] = b_lstm[i];
    for (int i = tid; i < 2 * HH; i += 512) sWmlp[i] = W_mlp[i];
    for (int i = tid; i < HH; i += 512) { hbuf[i] = 0.f; cbuf[i] = 0.f; }
    __syncthreads();
    for (int i = tid; i < FF * HH; i += 512) sWpe2[i] = W_pe[i] * bnsc[i / HH];
    for (int i = tid; i < HH; i += 512) {
        float a = b_pe[i];
        #pragma unroll
        for (int f = 0; f < FF; ++f) a = fmaf(bnsh[f], W_pe[f * HH + i], a);
        sbpe2[i] = a;
    }
    __syncthreads();
    // ---- input projection for t = 0 ----
    if (tid >= HH && tid < 2 * HH) {
        int u = tid - HH;
        const float* pr = pulse + (size_t)bb * TT * FF;
        float acc = sbpe2[u];
        #pragma unroll
        for (int f = 0; f < FF; ++f) acc = fmaf(pr[f], sWpe2[f * HH + u], acc);
        sbuf[u] = acc;
    }
    __syncthreads();

    // ---- encoder: 512 steps ----
    for (int t = 0; t < TT; ++t) {
        float z0 = sbl[2 * tid], z1 = sbl[2 * tid + 1];
        if constexpr (BF16W) {
            matvec2<true>(WxQ, sbuf, tid, z0, z1);
            matvec2<true>(WhQ, hbuf, tid, z0, z1);
        } else {
            matvec2<false>(W_x, sbuf, tid, z0, z1);
            matvec2<false>(W_h, hbuf, tid, z0, z1);
        }
        zbuf[2 * tid] = z0; zbuf[2 * tid + 1] = z1;
        __syncthreads();
        if (tid < HH) {
            float iv = zbuf[tid], fv = zbuf[tid + HH];
            float gv = zbuf[tid + 2 * HH], ov = zbuf[tid + 3 * HH];
            float c = sigmoidf_(fv) * cbuf[tid] + sigmoidf_(iv) * tanhf(gv);
            cbuf[tid] = c;
            hbuf[tid] = sigmoidf_(ov) * tanhf(c);
        } else if (tid < 2 * HH) {
            int u = tid - HH;
            float acc;
            if (t + 1 < TT) {
                const float* pr = pulse + ((size_t)bb * TT + (t + 1)) * FF;
                acc = sbpe2[u];
                #pragma unroll
                for (int f = 0; f < FF; ++f) acc = fmaf(pr[f], sWpe2[f * HH + u], acc);
            } else {
                acc = embed[u];   // decoder step-0 input
            }
            sbuf[u] = acc;
        }
        __syncthreads();
    }

    // ---- decoder: 35 autoregressive steps (inp == h for s >= 1 -> W_sum) ----
    for (int s = 0; s < DEC; ++s) {
        float z0 = sbl[2 * tid], z1 = sbl[2 * tid + 1];
        if (s == 0) {
            if constexpr (BF16W) {
                matvec2<true>(WxQ, sbuf, tid, z0, z1);
                matvec2<true>(WhQ, hbuf, tid, z0, z1);
            } else {
                matvec2<false>(W_x, sbuf, tid, z0, z1);
                matvec2<false>(W_h, hbuf, tid, z0, z1);
            }
        } else {
            if constexpr (BF16W) {
                matvec2<true>(WsQ, hbuf, tid, z0, z1);
            } else {
                matvec2<false>(W_x, hbuf, tid, z0, z1);
                matvec2<false>(W_h, hbuf, tid, z0, z1);
            }
        }
        zbuf[2 * tid] = z0; zbuf[2 * tid + 1] = z1;
        __syncthreads();
        if (tid < HH) {
            float iv = zbuf[tid], fv = zbuf[tid + HH];
            float gv = zbuf[tid + 2 * HH], ov = zbuf[tid + 3 * HH];
            float c = sigmoidf_(fv) * cbuf[tid] + sigmoidf_(iv) * tanhf(gv);
            cbuf[tid] = c;
            hbuf[tid] = sigmoidf_(ov) * tanhf(c);
        }
        __syncthreads();
        // pred = h @ W_mlp + b_mlp ; eis = pred*scale_w + scale_b
        if (tid < 128) {
            int j = tid >> 6, lane = tid & 63;
            float p = 0.f;
            #pragma unroll
            for (int u = lane; u < HH; u += 64) p = fmaf(hbuf[u], sWmlp[u * 2 + j], p);
            p += __shfl_down(p, 32); p += __shfl_down(p, 16); p += __shfl_down(p, 8);
            p += __shfl_down(p, 4);  p += __shfl_down(p, 2);  p += __shfl_down(p, 1);
            if (lane == 0) {
                float pr2 = p + smisc[j];
                out[((size_t)bb * DEC + s) * 2 + j] = pr2 * smisc[2 + j] + smisc[4 + j];
            }
        }
        __syncthreads();
    }
}

extern "C" void kernel_launch(void* const* d_in, const int* in_sizes, int n_in,
                              void* d_out, int out_size, void* d_ws, size_t ws_size,
                              hipStream_t stream) {
    const float* pulse    = (const float*)d_in[0];
    const float* bn_gamma = (const float*)d_in[1];
    const float* bn_beta  = (const float*)d_in[2];
    const float* bn_mean  = (const float*)d_in[3];
    const float* bn_var   = (const float*)d_in[4];
    const float* W_pe     = (const float*)d_in[5];
    const float* b_pe     = (const float*)d_in[6];
    const float* embed    = (const float*)d_in[7];
    const float* W_x      = (const float*)d_in[8];
    const float* W_h      = (const float*)d_in[9];
    const float* b_lstm   = (const float*)d_in[10];
    const float* W_mlp    = (const float*)d_in[11];
    const float* b_mlp    = (const float*)d_in[12];
    const float* scale_w  = (const float*)d_in[13];
    const float* scale_b  = (const float*)d_in[14];
    float* out = (float*)d_out;

    const size_t NW = (size_t)HH * H4;                 // 262144 per matrix
    bool use_bf16 = ws_size >= 3 * NW * sizeof(__hip_bfloat16);

    __hip_bfloat16* wxb = (__hip_bfloat16*)d_ws;
    __hip_bfloat16* whb = wxb + NW;
    __hip_bfloat16* wsb = whb + NW;

    if (use_bf16) {
        prep_weights<<<(int)((NW + 255) / 256), 256, 0, stream>>>(W_x, W_h, wxb, whb, wsb);
        lstm_persist<true><<<BB, 512, 0, stream>>>(
            pulse, bn_gamma, bn_beta, bn_mean, bn_var, W_pe, b_pe, embed,
            W_x, W_h, b_lstm, W_mlp, b_mlp, scale_w, scale_b,
            (const void*)wxb, (const void*)whb, (const void*)wsb, out);
    } else {
        lstm_persist<false><<<BB, 512, 0, stream>>>(
            pulse, bn_gamma, bn_beta, bn_mean, bn_var, W_pe, b_pe, embed,
            W_x, W_h, b_lstm, W_mlp, b_mlp, scale_w, scale_b,
            nullptr, nullptr, nullptr, out);
    }
}

// Round 3
// 8590.363 us; speedup vs baseline: 1.0011x; 1.0011x over previous
//
#include <hip/hip_runtime.h>
#include <hip/hip_bf16.h>
#include <stdint.h>

#define BB  256
#define TT  512
#define FF  8
#define HH  256
#define H4  1024
#define DEC 35
#define NWG 16
#define MW  16

typedef __attribute__((ext_vector_type(8))) short short8v;
typedef __attribute__((ext_vector_type(4))) float f32x4;

__device__ __forceinline__ unsigned short f2bf(float x) {
    unsigned u = __float_as_uint(x);
    u += 0x7fffu + ((u >> 16) & 1u);          // RNE
    return (unsigned short)(u >> 16);
}
__device__ __forceinline__ float bf2f(unsigned s) {
    return __uint_as_float(s << 16);
}
__device__ __forceinline__ float sigf(float x) {
    x = fminf(fmaxf(x, -30.f), 30.f);
    return 1.0f / (1.0f + __expf(-x));
}
__device__ __forceinline__ float tanh_(float x) {
    x = fminf(fmaxf(x, -15.f), 15.f);
    float e = __expf(2.0f * x);
    return (e - 1.0f) / (e + 1.0f);
}

// ============ path A prep kernels ============

// Wpx = bnscale * (W_pe @ W_x); zbias = b_lstm + b_pe@W_x + bnshift@(W_pe@W_x)
// zdec0 = b_lstm + embed@W_x.  grid 4x256 (one thread per n)
__global__ void prep_consts(const float* __restrict__ W_pe, const float* __restrict__ b_pe,
                            const float* __restrict__ embed, const float* __restrict__ W_x,
                            const float* __restrict__ b_lstm,
                            const float* __restrict__ bn_gamma, const float* __restrict__ bn_beta,
                            const float* __restrict__ bn_mean, const float* __restrict__ bn_var,
                            float* __restrict__ Wpx, float* __restrict__ zbias,
                            float* __restrict__ zdec0) {
    int n = blockIdx.x * 256 + threadIdx.x;
    float acc[FF];
    #pragma unroll
    for (int f = 0; f < FF; ++f) acc[f] = 0.f;
    float bsum = 0.f, dsum = 0.f;
    for (int m = 0; m < HH; ++m) {
        float wx = W_x[m * H4 + n];
        #pragma unroll
        for (int f = 0; f < FF; ++f) acc[f] = fmaf(W_pe[f * HH + m], wx, acc[f]);
        bsum = fmaf(b_pe[m], wx, bsum);
        dsum = fmaf(embed[m], wx, dsum);
    }
    float zb = b_lstm[n] + bsum;
    #pragma unroll
    for (int f = 0; f < FF; ++f) {
        float s  = bn_gamma[f] * rsqrtf(bn_var[f] + 1e-3f);
        float sh = bn_beta[f] - bn_mean[f] * s;
        Wpx[f * H4 + n] = s * acc[f];
        zb = fmaf(sh, acc[f], zb);
    }
    zbias[n] = zb;
    zdec0[n] = b_lstm[n] + dsum;
}

// weight fragments: whf/wsf[(nt*8+kc)*64 + lane] = 8 bf16 along K.
// B-frag layout: col = nt*16 + (lane&15), k = kc*32 + 8*(lane>>4) + j
__global__ void prep_wfrag(const float* __restrict__ W_x, const float* __restrict__ W_h,
                           short8v* __restrict__ whf, short8v* __restrict__ wsf) {
    int nt = blockIdx.x >> 3, kc = blockIdx.x & 7, ln = threadIdx.x;
    int n = nt * 16 + (ln & 15), q = ln >> 4;
    short8v vh, vs;
    #pragma unroll
    for (int j = 0; j < 8; ++j) {
        int k = kc * 32 + q * 8 + j;
        float wh = W_h[k * H4 + n], wx = W_x[k * H4 + n];
        vh[j] = (short)f2bf(wh);
        vs[j] = (short)f2bf(wx + wh);
    }
    whf[blockIdx.x * 64 + ln] = vh;
    wsf[blockIdx.x * 64 + ln] = vs;
}

// Zx[b,t,:] in D-fragment layout, bf16. block=(g,t), zxbuf[(g*512+t)*4096 + nt*64 + lane] = uint2 (4 bf16, r=0..3)
__global__ void prep_zx(const float* __restrict__ pulse, const float* __restrict__ Wpx,
                        const float* __restrict__ zbias, uint2* __restrict__ zxbuf) {
    int b = blockIdx.x, g = b >> 9, t = b & 511, tid = threadIdx.x;
    __shared__ float sp[MW * FF];
    if (tid < MW * FF) sp[tid] = pulse[((size_t)(g * MW + (tid >> 3)) * TT + t) * FF + (tid & 7)];
    __syncthreads();
    uint2* dst = zxbuf + (size_t)b * 4096;
    for (int it = 0; it < 16; ++it) {
        int e = it * 256 + tid;
        int ln = e & 63, nt = e >> 6;
        int col = ln & 15, q = ln >> 4, n = nt * 16 + col;
        float w[FF];
        #pragma unroll
        for (int f = 0; f < FF; ++f) w[f] = Wpx[f * H4 + n];
        float zb = zbias[n];
        unsigned short r[4];
        #pragma unroll
        for (int rr = 0; rr < 4; ++rr) {
            const float* pp = &sp[(4 * q + rr) * FF];
            float z = zb;
            #pragma unroll
            for (int f = 0; f < FF; ++f) z = fmaf(pp[f], w[f], z);
            r[rr] = f2bf(z);
        }
        uint2 o;
        o.x = ((unsigned)r[1] << 16) | r[0];
        o.y = ((unsigned)r[3] << 16) | r[2];
        dst[e] = o;
    }
}

// ============ path A main recurrent kernel ============
// 16 WGs x 512 thr; WG g owns batches [16g,16g+16). Wave w owns tiles {16*gate + 2w + p},
// so all 4 gates of units [32w,32w+32) land in its own accumulators; c-state in registers.
__global__ __launch_bounds__(512) void lstm_rec(
    const short8v* __restrict__ whf, const short8v* __restrict__ wsf,
    const uint2* __restrict__ zxbuf,
    const float* __restrict__ zdec0, const float* __restrict__ blstm,
    const float* __restrict__ W_mlp, const float* __restrict__ b_mlp,
    const float* __restrict__ scale_w, const float* __restrict__ scale_b,
    float* __restrict__ out) {
    __shared__ __align__(16) unsigned short hfr[2][8 * 64 * 8];  // [buf][kc][lane16][j] bf16 A-frags
    __shared__ float hb32[MW * 257];
    __shared__ float sWmlp[HH * 2];
    __shared__ float sm[6];

    const int tid = threadIdx.x, g = blockIdx.x;
    const int w = tid >> 6, ln = tid & 63;
    const int col = ln & 15, q = ln >> 4;

    for (int i = tid; i < 2 * 4096; i += 512) ((unsigned short*)hfr)[i] = 0;
    for (int i = tid; i < HH * 2; i += 512) sWmlp[i] = W_mlp[i];
    if (tid < 2) { sm[tid] = b_mlp[tid]; sm[2 + tid] = scale_w[tid]; sm[4 + tid] = scale_b[tid]; }
    float c[2][4];
    #pragma unroll
    for (int p = 0; p < 2; ++p)
        #pragma unroll
        for (int r = 0; r < 4; ++r) c[p][r] = 0.f;
    __syncthreads();

    int rb = 0;
    const uint2* zxg = zxbuf + (size_t)g * TT * 4096 + ln;

    // ---- encoder: 512 steps, 1 barrier each ----
    for (int t = 0; t < TT; ++t) {
        short8v a[8];
        const short8v* hfv = (const short8v*)hfr[rb];
        #pragma unroll
        for (int kc = 0; kc < 8; ++kc) a[kc] = hfv[kc * 64 + ln];
        const uint2* zx = zxg + (size_t)t * 4096;
        f32x4 acc[4][2];
        #pragma unroll
        for (int gg = 0; gg < 4; ++gg)
            #pragma unroll
            for (int p = 0; p < 2; ++p) {
                int nt = gg * 16 + 2 * w + p;
                uint2 z2 = zx[nt * 64];
                f32x4 av;
                av[0] = bf2f(z2.x & 0xffffu); av[1] = bf2f(z2.x >> 16);
                av[2] = bf2f(z2.y & 0xffffu); av[3] = bf2f(z2.y >> 16);
                const short8v* wp = whf + nt * 8 * 64 + ln;
                #pragma unroll
                for (int kc = 0; kc < 8; ++kc)
                    av = __builtin_amdgcn_mfma_f32_16x16x32_bf16(a[kc], wp[kc * 64], av, 0, 0, 0);
                acc[gg][p] = av;
            }
        unsigned short* hw = hfr[rb ^ 1];
        #pragma unroll
        for (int p = 0; p < 2; ++p)
            #pragma unroll
            for (int r = 0; r < 4; ++r) {
                float zi = acc[0][p][r], zf = acc[1][p][r], zg = acc[2][p][r], zo = acc[3][p][r];
                float cc = sigf(zf) * c[p][r] + sigf(zi) * tanh_(zg);
                c[p][r] = cc;
                float hh = sigf(zo) * tanh_(cc);
                hw[((w * 64) + (2 * p + (col >> 3)) * 16 + 4 * q + r) * 8 + (col & 7)] = f2bf(hh);
            }
        __syncthreads();
        rb ^= 1;
    }

    // ---- decoder: 35 steps (s=0: W_h + zdec0; s>=1: W_sum + b_lstm) ----
    for (int s = 0; s < DEC; ++s) {
        short8v a[8];
        const short8v* hfv = (const short8v*)hfr[rb];
        #pragma unroll
        for (int kc = 0; kc < 8; ++kc) a[kc] = hfv[kc * 64 + ln];
        const short8v* wsel = (s == 0) ? whf : wsf;
        const float*  bsel  = (s == 0) ? zdec0 : blstm;
        f32x4 acc[4][2];
        #pragma unroll
        for (int gg = 0; gg < 4; ++gg)
            #pragma unroll
            for (int p = 0; p < 2; ++p) {
                int nt = gg * 16 + 2 * w + p;
                float bv = bsel[nt * 16 + col];
                f32x4 av; av[0] = bv; av[1] = bv; av[2] = bv; av[3] = bv;
                const short8v* wp = wsel + nt * 8 * 64 + ln;
                #pragma unroll
                for (int kc = 0; kc < 8; ++kc)
                    av = __builtin_amdgcn_mfma_f32_16x16x32_bf16(a[kc], wp[kc * 64], av, 0, 0, 0);
                acc[gg][p] = av;
            }
        unsigned short* hw = hfr[rb ^ 1];
        #pragma unroll
        for (int p = 0; p < 2; ++p)
            #pragma unroll
            for (int r = 0; r < 4; ++r) {
                float zi = acc[0][p][r], zf = acc[1][p][r], zg = acc[2][p][r], zo = acc[3][p][r];
                float cc = sigf(zf) * c[p][r] + sigf(zi) * tanh_(zg);
                c[p][r] = cc;
                float hh = sigf(zo) * tanh_(cc);
                hw[((w * 64) + (2 * p + (col >> 3)) * 16 + 4 * q + r) * 8 + (col & 7)] = f2bf(hh);
                hb32[(4 * q + r) * 257 + (32 * w + 16 * p + col)] = hh;
            }
        __syncthreads();
        // MLP head: pred = h@W_mlp + b_mlp; eis = pred*sw + sb
        {
            int m = tid >> 5, j = (tid >> 4) & 1, uc = tid & 15;
            float p2 = 0.f;
            #pragma unroll
            for (int i = 0; i < 16; ++i) {
                int u = i * 16 + uc;
                p2 = fmaf(hb32[m * 257 + u], sWmlp[u * 2 + j], p2);
            }
            p2 += __shfl_down(p2, 8, 16);
            p2 += __shfl_down(p2, 4, 16);
            p2 += __shfl_down(p2, 2, 16);
            p2 += __shfl_down(p2, 1, 16);
            if (uc == 0) {
                float pr = p2 + sm[j];
                out[((size_t)(g * MW + m) * DEC + s) * 2 + j] = pr * sm[2 + j] + sm[4 + j];
            }
        }
        __syncthreads();
        rb ^= 1;
    }
}

// ============ fallback (round-2, passing) ============
__global__ void prep_weights(const float* __restrict__ Wx, const float* __restrict__ Wh,
                             __hip_bfloat16* __restrict__ wxb,
                             __hip_bfloat16* __restrict__ whb,
                             __hip_bfloat16* __restrict__ wsb) {
    int i = blockIdx.x * 256 + threadIdx.x;
    if (i < HH * H4) {
        float x = Wx[i], h = Wh[i];
        wxb[i] = __float2bfloat16(x);
        whb[i] = __float2bfloat16(h);
        wsb[i] = __float2bfloat16(x + h);
    }
}

template<bool BF16W>
__device__ __forceinline__ void matvec2(const void* __restrict__ W,
                                        const float* __restrict__ vec,
                                        int tid, float& z0, float& z1) {
    if constexpr (BF16W) {
        const uint32_t* Wp = (const uint32_t*)W;
        #pragma unroll 8
        for (int k = 0; k < HH; ++k) {
            uint32_t w = Wp[(size_t)k * (H4 / 2) + tid];
            float s = vec[k];
            union { uint32_t u; float f; } lo, hi;
            lo.u = w << 16;
            hi.u = w & 0xffff0000u;
            z0 = fmaf(s, lo.f, z0);
            z1 = fmaf(s, hi.f, z1);
        }
    } else {
        const float2* Wp = (const float2*)W;
        #pragma unroll 8
        for (int k = 0; k < HH; ++k) {
            float2 w = Wp[(size_t)k * (H4 / 2) + tid];
            float s = vec[k];
            z0 = fmaf(s, w.x, z0);
            z1 = fmaf(s, w.y, z1);
        }
    }
}

__device__ __forceinline__ float sigmoidf_(float x) { return 1.0f / (1.0f + expf(-x)); }

template<bool BF16W>
__global__ __launch_bounds__(512)
void lstm_persist(const float* __restrict__ pulse,
                  const float* __restrict__ bn_gamma, const float* __restrict__ bn_beta,
                  const float* __restrict__ bn_mean, const float* __restrict__ bn_var,
                  const float* __restrict__ W_pe, const float* __restrict__ b_pe,
                  const float* __restrict__ embed,
                  const float* __restrict__ W_x, const float* __restrict__ W_h,
                  const float* __restrict__ b_lstm,
                  const float* __restrict__ W_mlp, const float* __restrict__ b_mlp,
                  const float* __restrict__ scale_w, const float* __restrict__ scale_b,
                  const void* __restrict__ WxQ, const void* __restrict__ WhQ,
                  const void* __restrict__ WsQ,
                  float* __restrict__ out) {
    __shared__ float sWpe2[FF * HH];
    __shared__ float sbpe2[HH];
    __shared__ float sbl[H4];
    __shared__ float sWmlp[HH * 2];
    __shared__ float sbuf[HH];
    __shared__ float hbuf[HH];
    __shared__ float cbuf[HH];
    __shared__ float zbuf[H4];
    __shared__ float bnsc[FF], bnsh[FF];
    __shared__ float smisc[6];

    const int tid = threadIdx.x;
    const int bb  = blockIdx.x;

    if (tid < FF) {
        float s = bn_gamma[tid] * rsqrtf(bn_var[tid] + 1e-3f);
        bnsc[tid] = s;
        bnsh[tid] = bn_beta[tid] - bn_mean[tid] * s;
    }
    if (tid < 2) {
        smisc[tid]     = b_mlp[tid];
        smisc[2 + tid] = scale_w[tid];
        smisc[4 + tid] = scale_b[tid];
    }
    for (int i = tid; i < H4; i += 512) sbl[i] = b_lstm[i];
    for (int i = tid; i < 2 * HH; i += 512) sWmlp[i] = W_mlp[i];
    for (int i = tid; i < HH; i += 512) { hbuf[i] = 0.f; cbuf[i] = 0.f; }
    __syncthreads();
    for (int i = tid; i < FF * HH; i += 512) sWpe2[i] = W_pe[i] * bnsc[i / HH];
    for (int i = tid; i < HH; i += 512) {
        float a = b_pe[i];
        #pragma unroll
        for (int f = 0; f < FF; ++f) a = fmaf(bnsh[f], W_pe[f * HH + i], a);
        sbpe2[i] = a;
    }
    __syncthreads();
    if (tid >= HH && tid < 2 * HH) {
        int u = tid - HH;
        const float* pr = pulse + (size_t)bb * TT * FF;
        float acc = sbpe2[u];
        #pragma unroll
        for (int f = 0; f < FF; ++f) acc = fmaf(pr[f], sWpe2[f * HH + u], acc);
        sbuf[u] = acc;
    }
    __syncthreads();

    for (int t = 0; t < TT; ++t) {
        float z0 = sbl[2 * tid], z1 = sbl[2 * tid + 1];
        if constexpr (BF16W) {
            matvec2<true>(WxQ, sbuf, tid, z0, z1);
            matvec2<true>(WhQ, hbuf, tid, z0, z1);
        } else {
            matvec2<false>(W_x, sbuf, tid, z0, z1);
            matvec2<false>(W_h, hbuf, tid, z0, z1);
        }
        zbuf[2 * tid] = z0; zbuf[2 * tid + 1] = z1;
        __syncthreads();
        if (tid < HH) {
            float iv = zbuf[tid], fv = zbuf[tid + HH];
            float gv = zbuf[tid + 2 * HH], ov = zbuf[tid + 3 * HH];
            float c = sigmoidf_(fv) * cbuf[tid] + sigmoidf_(iv) * tanhf(gv);
            cbuf[tid] = c;
            hbuf[tid] = sigmoidf_(ov) * tanhf(c);
        } else if (tid < 2 * HH) {
            int u = tid - HH;
            float acc;
            if (t + 1 < TT) {
                const float* pr = pulse + ((size_t)bb * TT + (t + 1)) * FF;
                acc = sbpe2[u];
                #pragma unroll
                for (int f = 0; f < FF; ++f) acc = fmaf(pr[f], sWpe2[f * HH + u], acc);
            } else {
                acc = embed[u];
            }
            sbuf[u] = acc;
        }
        __syncthreads();
    }

    for (int s = 0; s < DEC; ++s) {
        float z0 = sbl[2 * tid], z1 = sbl[2 * tid + 1];
        if (s == 0) {
            if constexpr (BF16W) {
                matvec2<true>(WxQ, sbuf, tid, z0, z1);
                matvec2<true>(WhQ, hbuf, tid, z0, z1);
            } else {
                matvec2<false>(W_x, sbuf, tid, z0, z1);
                matvec2<false>(W_h, hbuf, tid, z0, z1);
            }
        } else {
            if constexpr (BF16W) {
                matvec2<true>(WsQ, hbuf, tid, z0, z1);
            } else {
                matvec2<false>(W_x, hbuf, tid, z0, z1);
                matvec2<false>(W_h, hbuf, tid, z0, z1);
            }
        }
        zbuf[2 * tid] = z0; zbuf[2 * tid + 1] = z1;
        __syncthreads();
        if (tid < HH) {
            float iv = zbuf[tid], fv = zbuf[tid + HH];
            float gv = zbuf[tid + 2 * HH], ov = zbuf[tid + 3 * HH];
            float c = sigmoidf_(fv) * cbuf[tid] + sigmoidf_(iv) * tanhf(gv);
            cbuf[tid] = c;
            hbuf[tid] = sigmoidf_(ov) * tanhf(c);
        }
        __syncthreads();
        if (tid < 128) {
            int j = tid >> 6, lane = tid & 63;
            float p = 0.f;
            #pragma unroll
            for (int u = lane; u < HH; u += 64) p = fmaf(hbuf[u], sWmlp[u * 2 + j], p);
            p += __shfl_down(p, 32); p += __shfl_down(p, 16); p += __shfl_down(p, 8);
            p += __shfl_down(p, 4);  p += __shfl_down(p, 2);  p += __shfl_down(p, 1);
            if (lane == 0) {
                float pr2 = p + smisc[j];
                out[((size_t)bb * DEC + s) * 2 + j] = pr2 * smisc[2 + j] + smisc[4 + j];
            }
        }
        __syncthreads();
    }
}

extern "C" void kernel_launch(void* const* d_in, const int* in_sizes, int n_in,
                              void* d_out, int out_size, void* d_ws, size_t ws_size,
                              hipStream_t stream) {
    const float* pulse    = (const float*)d_in[0];
    const float* bn_gamma = (const float*)d_in[1];
    const float* bn_beta  = (const float*)d_in[2];
    const float* bn_mean  = (const float*)d_in[3];
    const float* bn_var   = (const float*)d_in[4];
    const float* W_pe     = (const float*)d_in[5];
    const float* b_pe     = (const float*)d_in[6];
    const float* embed    = (const float*)d_in[7];
    const float* W_x      = (const float*)d_in[8];
    const float* W_h      = (const float*)d_in[9];
    const float* b_lstm   = (const float*)d_in[10];
    const float* W_mlp    = (const float*)d_in[11];
    const float* b_mlp    = (const float*)d_in[12];
    const float* scale_w  = (const float*)d_in[13];
    const float* scale_b  = (const float*)d_in[14];
    float* out = (float*)d_out;

    const size_t ZXB   = (size_t)NWG * TT * 4096 * sizeof(uint2);   // 256 MB
    const size_t WFRAG = (size_t)64 * 8 * 64 * 16;                  // 512 KB
    const size_t needA = ZXB + 2 * WFRAG + (size_t)FF * H4 * 4 + 2 * H4 * 4;

    if (ws_size >= needA) {
        uint2*   zxbuf = (uint2*)d_ws;
        short8v* whf   = (short8v*)((char*)d_ws + ZXB);
        short8v* wsf   = (short8v*)((char*)d_ws + ZXB + WFRAG);
        float*   Wpx   = (float*)((char*)d_ws + ZXB + 2 * WFRAG);
        float*   zbias = Wpx + FF * H4;
        float*   zdec0 = zbias + H4;
        prep_consts<<<4, 256, 0, stream>>>(W_pe, b_pe, embed, W_x, b_lstm,
                                           bn_gamma, bn_beta, bn_mean, bn_var,
                                           Wpx, zbias, zdec0);
        prep_wfrag<<<512, 64, 0, stream>>>(W_x, W_h, whf, wsf);
        prep_zx<<<NWG * TT, 256, 0, stream>>>(pulse, Wpx, zbias, zxbuf);
        lstm_rec<<<NWG, 512, 0, stream>>>(whf, wsf, zxbuf, zdec0, b_lstm,
                                          W_mlp, b_mlp, scale_w, scale_b, out);
        return;
    }

    const size_t NW = (size_t)HH * H4;
    bool use_bf16 = ws_size >= 3 * NW * sizeof(__hip_bfloat16);
    __hip_bfloat16* wxb = (__hip_bfloat16*)d_ws;
    __hip_bfloat16* whb = wxb + NW;
    __hip_bfloat16* wsb = whb + NW;

    if (use_bf16) {
        prep_weights<<<(int)((NW + 255) / 256), 256, 0, stream>>>(W_x, W_h, wxb, whb, wsb);
        lstm_persist<true><<<BB, 512, 0, stream>>>(
            pulse, bn_gamma, bn_beta, bn_mean, bn_var, W_pe, b_pe, embed,
            W_x, W_h, b_lstm, W_mlp, b_mlp, scale_w, scale_b,
            (const void*)wxb, (const void*)whb, (const void*)wsb, out);
    } else {
        lstm_persist<false><<<BB, 512, 0, stream>>>(
            pulse, bn_gamma, bn_beta, bn_mean, bn_var, W_pe, b_pe, embed,
            W_x, W_h, b_lstm, W_mlp, b_mlp, scale_w, scale_b,
            nullptr, nullptr, nullptr, out);
    }
}